// Round 1
// baseline (2598.379 us; speedup 1.0000x reference)
//
#include <hip/hip_runtime.h>
#include <math.h>

#define B_   24
#define NA_  50
#define T_   10
#define NV_  196
#define D_   512
#define M_   (B_ * NA_)    // 1200 audio rows
#define VR_  (B_ * T_ * NV_) // 47040 visual rows
#define ROWT 32
#define COLT 224           // 196 padded to 7*32
#define BK   32
#define LDST 34            // LDS row stride (floats): even (float2-aligned), non-pow2 (bank-safe)

// ---------------- inverse L2 norm per row of 512 ----------------
__global__ void norm_kernel(const float* __restrict__ x, float* __restrict__ inv, int rows) {
    int w    = threadIdx.x >> 6;       // wave in block (4 waves)
    int lane = threadIdx.x & 63;
    int row  = blockIdx.x * 4 + w;
    if (row >= rows) return;
    const float* p = x + (size_t)row * D_ + lane * 8;
    float4 u = *reinterpret_cast<const float4*>(p);
    float4 v = *reinterpret_cast<const float4*>(p + 4);
    float s = u.x*u.x + u.y*u.y + u.z*u.z + u.w*u.w
            + v.x*v.x + v.y*v.y + v.z*v.z + v.w*v.w;
    #pragma unroll
    for (int off = 32; off; off >>= 1) s += __shfl_xor(s, off, 64);
    if (lane == 0) inv[row] = 1.0f / fmaxf(sqrtf(s), 1e-12f);
}

// ---------------- fused similarity GEMM + max/clip reductions ----------------
// grid: (ceil(M/ROWT)=38, B*T=240).  block: 256.
// Computes sims for 32 audio rows x 196 v-cols, writes per-(row,t) max over v,
// atomically accumulates sum of clip(s,-20,0)^2.
__global__ __launch_bounds__(256) void simred_kernel(
    const float* __restrict__ A, const float* __restrict__ Vf,
    const float* __restrict__ invA, const float* __restrict__ invV,
    const float* __restrict__ tempPtr,
    float* __restrict__ maxvis, float* __restrict__ accNonneg)
{
    __shared__ float As[ROWT][LDST];
    __shared__ float Vs[COLT][LDST];
    __shared__ float redbuf[4];

    const int tid = threadIdx.x;
    const int tx  = tid & 31;          // col lane
    const int ty  = tid >> 5;          // row group (0..7)
    const int rowBase = blockIdx.x * ROWT;
    const int yt      = blockIdx.y;    // y*T + t
    const int colBase = yt * NV_;      // row index into visual (47040 rows)
    const float invT  = 1.0f / tempPtr[0];

    // staging assignment: A — thread loads one float4: row tid>>3, k-off (tid&7)*4
    const int ar  = tid >> 3;
    const int ak  = (tid & 7) * 4;
    const int gar = rowBase + ar;
    const float sA = (gar < M_) ? invA[gar] * invT : 0.0f;

    // staging assignment: V — 7 float4 per thread
    float sV[7];
    #pragma unroll
    for (int j = 0; j < 7; ++j) {
        int idx = tid + 256 * j;
        int vr  = idx >> 3;
        sV[j] = (vr < NV_) ? invV[colBase + vr] : 0.0f;
    }

    float acc[4][7];
    #pragma unroll
    for (int i = 0; i < 4; ++i)
        #pragma unroll
        for (int j = 0; j < 7; ++j) acc[i][j] = 0.0f;

    for (int kc = 0; kc < D_; kc += BK) {
        __syncthreads();   // previous iter's LDS reads complete
        // stage A (scaled by inv_norm/temperature)
        {
            float4 u = make_float4(0.f, 0.f, 0.f, 0.f);
            if (gar < M_) u = *reinterpret_cast<const float4*>(A + (size_t)gar * D_ + kc + ak);
            As[ar][ak + 0] = u.x * sA;
            As[ar][ak + 1] = u.y * sA;
            As[ar][ak + 2] = u.z * sA;
            As[ar][ak + 3] = u.w * sA;
        }
        // stage V (scaled by inv_norm)
        #pragma unroll
        for (int j = 0; j < 7; ++j) {
            int idx = tid + 256 * j;
            int vr  = idx >> 3;
            int vk  = (idx & 7) * 4;
            float4 u = make_float4(0.f, 0.f, 0.f, 0.f);
            if (vr < NV_) u = *reinterpret_cast<const float4*>(Vf + (size_t)(colBase + vr) * D_ + kc + vk);
            float s = sV[j];
            Vs[vr][vk + 0] = u.x * s;
            Vs[vr][vk + 1] = u.y * s;
            Vs[vr][vk + 2] = u.z * s;
            Vs[vr][vk + 3] = u.w * s;
        }
        __syncthreads();
        // compute: k unrolled by 2 via float2 LDS reads
        #pragma unroll
        for (int k2 = 0; k2 < BK / 2; ++k2) {
            float2 av[4], vv[7];
            #pragma unroll
            for (int i = 0; i < 4; ++i)
                av[i] = *reinterpret_cast<const float2*>(&As[ty * 4 + i][k2 * 2]);
            #pragma unroll
            for (int j = 0; j < 7; ++j)
                vv[j] = *reinterpret_cast<const float2*>(&Vs[tx + 32 * j][k2 * 2]);
            #pragma unroll
            for (int i = 0; i < 4; ++i)
                #pragma unroll
                for (int j = 0; j < 7; ++j) {
                    acc[i][j] += av[i].x * vv[j].x;
                    acc[i][j] += av[i].y * vv[j].y;
                }
        }
    }

    // ---- clip(s,-20,0)^2 partial sum (padding contributes exact 0) ----
    float cs = 0.0f;
    #pragma unroll
    for (int i = 0; i < 4; ++i)
        #pragma unroll
        for (int j = 0; j < 7; ++j) {
            float c = fminf(fmaxf(acc[i][j], -20.0f), 0.0f);
            cs += c * c;
        }
    #pragma unroll
    for (int off = 32; off; off >>= 1) cs += __shfl_xor(cs, off, 64);
    if ((tid & 63) == 0) redbuf[tid >> 6] = cs;
    __syncthreads();
    if (tid == 0)
        atomicAdd(accNonneg, redbuf[0] + redbuf[1] + redbuf[2] + redbuf[3]);

    // ---- per-row max over the 196 valid cols ----
    const int y = yt / T_;
    const int t = yt % T_;
    #pragma unroll
    for (int i = 0; i < 4; ++i) {
        float m = -1e30f;
        #pragma unroll
        for (int j = 0; j < 7; ++j) {
            int col = tx + 32 * j;
            if (col < NV_) m = fmaxf(m, acc[i][j]);
        }
        #pragma unroll
        for (int off = 16; off; off >>= 1) m = fmaxf(m, __shfl_xor(m, off, 32));
        if (tx == 0) {
            int gr = rowBase + ty * 4 + i;
            if (gr < M_) {
                int x = gr / NA_;
                int a = gr % NA_;
                maxvis[(((size_t)x * B_ + y) * NA_ + a) * T_ + t] = m;
            }
        }
    }
}

// ---------------- per-(x,y) aggregation over (a,t) ----------------
// grid: B*B=576 blocks, 64 threads (thread a<50 handles one audio token)
__global__ void aggregate_kernel(const float* __restrict__ maxvis,
                                 const float* __restrict__ thrPtr,
                                 const float* __restrict__ scalePtr,
                                 float* __restrict__ clipSims,
                                 float* __restrict__ accFrac,
                                 float* __restrict__ accSel)
{
    int xy = blockIdx.x;
    int x = xy / B_, y = xy % B_;
    int a = threadIdx.x;
    float th    = 1.0f / (1.0f + expf(-thrPtr[0]));
    float scale = scalePtr[0];
    float token = 0.0f, cnt = 0.0f, selsum = 0.0f;
    if (a < NA_) {
        const float* p = maxvis + (((size_t)x * B_ + y) * NA_ + a) * T_;
        float ws = 0.0f, ss = 0.0f;
        #pragma unroll
        for (int t = 0; t < T_; ++t) {
            float mv  = p[t];
            float rd  = mv - th;
            float sel = fmaxf(rd, 0.0f) * scale;
            ws += mv * sel;
            ss += sel;
            if (rd > 0.0f) cnt += 1.0f;
            if (x == y) selsum += 0.5f * (tanhf(20.0f * rd) + 1.0f);
        }
        token = ws / fmaxf(ss, 1e-6f);
    }
    #pragma unroll
    for (int off = 32; off; off >>= 1) {
        token  += __shfl_xor(token,  off, 64);
        cnt    += __shfl_xor(cnt,    off, 64);
        selsum += __shfl_xor(selsum, off, 64);
    }
    if (threadIdx.x == 0) {
        clipSims[x * B_ + y] = token / (float)NA_;
        atomicAdd(accFrac, cnt);
        if (x == y) atomicAdd(accSel, selsum);
    }
}

// ---------------- finalize: InfoNCE + reg terms -> 5 scalars ----------------
__global__ void finalize_kernel(const float* __restrict__ clipSims,
                                const float* __restrict__ accs,   // [nonneg_sum, frac_cnt, sel_sum]
                                const float* __restrict__ tempPtr,
                                const float* __restrict__ scalePtr,
                                const float* __restrict__ thrPtr,
                                float* __restrict__ out)
{
    __shared__ float cs[B_ * B_];
    int tid = threadIdx.x;  // 64
    for (int i = tid; i < B_ * B_; i += 64) cs[i] = clipSims[i];
    __syncthreads();
    float lsum = 0.0f;
    if (tid < B_) {
        int i = tid;
        float m = -1e30f;
        for (int j = 0; j < B_; ++j) m = fmaxf(m, cs[i * B_ + j]);
        float e = 0.0f;
        for (int j = 0; j < B_; ++j) e += expf(cs[i * B_ + j] - m);
        float la = m + logf(e) - cs[i * B_ + i];
        float m2 = -1e30f;
        for (int j = 0; j < B_; ++j) m2 = fmaxf(m2, cs[j * B_ + i]);
        float e2 = 0.0f;
        for (int j = 0; j < B_; ++j) e2 += expf(cs[j * B_ + i] - m2);
        float lv = m2 + logf(e2) - cs[i * B_ + i];
        lsum = la + lv;
    }
    #pragma unroll
    for (int off = 32; off; off >>= 1) lsum += __shfl_xor(lsum, off, 64);
    if (tid == 0) {
        float contrastive = lsum / (float)B_ * 0.5f;
        float temp = tempPtr[0], scl = scalePtr[0];
        float th = 1.0f / (1.0f + expf(-thrPtr[0]));
        float l_nonneg = accs[0] / 56448000.0f;   // B*B*NA*T*NV
        float logt = logf(temp);
        float tl  = fmaxf(-logt, 0.0f);
        float thi = fmaxf(logt - logf(4.0f), 0.0f);
        float l_cal = tl * tl + thi * thi;
        float t1 = fmaxf(th - 0.9f, 0.0f), t2 = fmaxf(0.1f - th, 0.0f);
        float l_thr = t1 * t1 + t2 * t2;
        float s1 = fmaxf(scl - 20.0f, 0.0f), s2 = fmaxf(1.0f - scl, 0.0f);
        float l_scale = s1 * s1 + s2 * s2;
        float reg = 0.15f * l_nonneg + 2.0f * l_cal + 0.1f * l_thr + 0.1f * l_scale;
        float frac   = accs[1] / 288000.0f;       // B*B*NA*T
        float selrew = -0.1f * log1pf(accs[2] / 12000.0f); // B*NA*T
        float total  = selrew + contrastive + reg;
        out[0] = total;
        out[1] = contrastive;
        out[2] = reg;
        out[3] = frac;
        out[4] = selrew;
    }
}

extern "C" void kernel_launch(void* const* d_in, const int* in_sizes, int n_in,
                              void* d_out, int out_size, void* d_ws, size_t ws_size,
                              hipStream_t stream) {
    const float* audio  = (const float*)d_in[0];  // (24,50,512)
    const float* visual = (const float*)d_in[1];  // (24,10,196,512)
    const float* temp   = (const float*)d_in[2];
    const float* scale  = (const float*)d_in[3];
    const float* thr    = (const float*)d_in[4];
    float* out = (float*)d_out;

    float* ws       = (float*)d_ws;
    float* invA     = ws;               // 1200
    float* invV     = ws + 1200;        // 47040
    float* maxvis   = ws + 48240;       // 288000
    float* clipSims = ws + 336240;      // 576
    float* accs     = ws + 336816;      // 3: [nonneg, frac, sel]

    hipMemsetAsync(accs, 0, 3 * sizeof(float), stream);

    norm_kernel<<<M_ / 4, 256, 0, stream>>>(audio, invA, M_);
    norm_kernel<<<VR_ / 4, 256, 0, stream>>>(visual, invV, VR_);

    dim3 grid((M_ + ROWT - 1) / ROWT, B_ * T_);
    simred_kernel<<<grid, 256, 0, stream>>>(audio, visual, invA, invV, temp, maxvis, accs);

    aggregate_kernel<<<B_ * B_, 64, 0, stream>>>(maxvis, thr, scale, clipSims, accs + 1, accs + 2);
    finalize_kernel<<<1, 64, 0, stream>>>(clipSims, accs, temp, scale, thr, out);
}

// Round 2
// 290.389 us; speedup vs baseline: 8.9479x; 8.9479x over previous
//
#include <hip/hip_runtime.h>
#include <math.h>

#define B_   24
#define NA_  50
#define T_   10
#define NV_  196
#define D_   512
#define M_   1200          // B*NA audio rows
#define MPAD 1280          // padded to 10 tiles of 128
#define NVP  224           // 196 padded to 14*16
#define YT_  240           // B*T
#define VROWS (YT_ * NVP)  // 53760 padded visual rows

typedef __bf16 bf16x8 __attribute__((ext_vector_type(8)));
typedef float  f32x4  __attribute__((ext_vector_type(4)));
typedef unsigned short ushort8 __attribute__((ext_vector_type(8)));

__device__ __forceinline__ unsigned short f2bf(float f) {
    unsigned u = __float_as_uint(f);
    u += 0x7FFF + ((u >> 16) & 1);       // RNE
    return (unsigned short)(u >> 16);
}

__device__ __forceinline__ void gload16(const void* g, void* l) {
    __builtin_amdgcn_global_load_lds(
        (const __attribute__((address_space(1))) unsigned int*)g,
        (__attribute__((address_space(3))) unsigned int*)l, 16, 0, 0);
}

// ---- fused L2-normalize + scale + bf16 convert, audio: (1200,512) -> (1280,512) bf16 ----
__global__ void normconvA_kernel(const float* __restrict__ a,
                                 const float* __restrict__ tempPtr,
                                 unsigned short* __restrict__ Abf) {
    int w = threadIdx.x >> 6, lane = threadIdx.x & 63;
    int row = blockIdx.x * 4 + w;
    if (row >= MPAD) return;
    ushort8* dst = (ushort8*)(Abf + (size_t)row * D_ + lane * 8);
    if (row < M_) {
        const float* p = a + (size_t)row * D_ + lane * 8;
        float4 u = *(const float4*)p;
        float4 v = *(const float4*)(p + 4);
        float s = u.x*u.x + u.y*u.y + u.z*u.z + u.w*u.w
                + v.x*v.x + v.y*v.y + v.z*v.z + v.w*v.w;
        #pragma unroll
        for (int off = 32; off; off >>= 1) s += __shfl_xor(s, off, 64);
        float sc = 1.0f / (fmaxf(sqrtf(s), 1e-12f) * tempPtr[0]);
        ushort8 o;
        o[0]=f2bf(u.x*sc); o[1]=f2bf(u.y*sc); o[2]=f2bf(u.z*sc); o[3]=f2bf(u.w*sc);
        o[4]=f2bf(v.x*sc); o[5]=f2bf(v.y*sc); o[6]=f2bf(v.z*sc); o[7]=f2bf(v.w*sc);
        *dst = o;
    } else {
        ushort8 z = (ushort8)0;
        *dst = z;
    }
}

// ---- visual: (240*196,512) -> (240*224,512) bf16, zero pad rows ----
__global__ void normconvV_kernel(const float* __restrict__ vf,
                                 unsigned short* __restrict__ Vbf) {
    int w = threadIdx.x >> 6, lane = threadIdx.x & 63;
    int row = blockIdx.x * 4 + w;
    if (row >= VROWS) return;
    int yt = row / NVP, vv = row - yt * NVP;
    ushort8* dst = (ushort8*)(Vbf + (size_t)row * D_ + lane * 8);
    if (vv < NV_) {
        const float* p = vf + ((size_t)yt * NV_ + vv) * D_ + lane * 8;
        float4 u = *(const float4*)p;
        float4 v = *(const float4*)(p + 4);
        float s = u.x*u.x + u.y*u.y + u.z*u.z + u.w*u.w
                + v.x*v.x + v.y*v.y + v.z*v.z + v.w*v.w;
        #pragma unroll
        for (int off = 32; off; off >>= 1) s += __shfl_xor(s, off, 64);
        float sc = 1.0f / fmaxf(sqrtf(s), 1e-12f);
        ushort8 o;
        o[0]=f2bf(u.x*sc); o[1]=f2bf(u.y*sc); o[2]=f2bf(u.z*sc); o[3]=f2bf(u.w*sc);
        o[4]=f2bf(v.x*sc); o[5]=f2bf(v.y*sc); o[6]=f2bf(v.z*sc); o[7]=f2bf(v.w*sc);
        *dst = o;
    } else {
        ushort8 z = (ushort8)0;
        *dst = z;
    }
}

// ---- MFMA GEMM + fused max/clip reductions ----
// grid: (10, 240). block: 256 (4 waves, 2x2). Block tile: 128 rows x 224 cols, K=512.
__global__ __launch_bounds__(256) void simred_kernel(
    const unsigned short* __restrict__ Abf, const unsigned short* __restrict__ Vbf,
    float* __restrict__ maxvis, float* __restrict__ accNonneg)
{
    __shared__ __align__(16) unsigned char lds[8192 + 14336]; // As[128][32bf16] | Vs[224][32bf16]
    __shared__ float maxred[2][128];
    __shared__ float redbuf[4];

    const int tid  = threadIdx.x;
    const int lane = tid & 63;
    const int w    = tid >> 6;
    const int lrow = lane >> 2;    // staging: row within 16-row unit
    const int lcol = lane & 3;     // staging: 16B piece within 64B row
    const int q    = lane >> 4;    // frag quad
    const int m16  = lane & 15;
    const int wr   = w & 1;        // wave row half (64 rows)
    const int wc   = w >> 1;       // wave col half (112 cols)
    const int rowA0 = blockIdx.x * 128;
    const int yt    = blockIdx.y;
    const size_t vRow0 = (size_t)yt * NVP;

    // staging units: 0..7 = A rows u*16.., 8..21 = V rows (u-8)*16..
    const unsigned short* gp[6];
    const unsigned char*  lp[6];
    int nun = 0;
    for (int u = w; u < 22; u += 4) {
        if (u < 8) gp[nun] = Abf + ((size_t)(rowA0 + u * 16 + lrow)) * D_ + lcol * 8;
        else       gp[nun] = Vbf + (vRow0 + (size_t)((u - 8) * 16 + lrow)) * D_ + lcol * 8;
        lp[nun] = lds + u * 1024;
        ++nun;
    }

    // fragment LDS pointers (A[m][k]: m=lane&15, k=q*8+j ; B same)
    const unsigned char* aP[4];
    const unsigned char* bP[7];
    #pragma unroll
    for (int i = 0; i < 4; ++i) aP[i] = lds + (size_t)(wr * 64 + i * 16 + m16) * 64 + q * 16;
    #pragma unroll
    for (int j = 0; j < 7; ++j) bP[j] = lds + 8192 + (size_t)(wc * 112 + j * 16 + m16) * 64 + q * 16;

    f32x4 acc[4][7];
    #pragma unroll
    for (int i = 0; i < 4; ++i)
        #pragma unroll
        for (int j = 0; j < 7; ++j) acc[i][j] = (f32x4)0.0f;

    for (int c = 0; c < 16; ++c) {
        const int kc = c * 32;
        __syncthreads();                       // prev chunk's frag reads done
        #pragma unroll 6
        for (int i = 0; i < 6; ++i)
            if (i < nun) gload16(gp[i] + kc, (void*)lp[i]);
        __syncthreads();                       // staging complete (vmcnt drained)
        bf16x8 af[4], bfr[7];
        #pragma unroll
        for (int i = 0; i < 4; ++i) af[i] = *(const bf16x8*)aP[i];
        #pragma unroll
        for (int j = 0; j < 7; ++j) bfr[j] = *(const bf16x8*)bP[j];
        #pragma unroll
        for (int i = 0; i < 4; ++i)
            #pragma unroll
            for (int j = 0; j < 7; ++j)
                acc[i][j] = __builtin_amdgcn_mfma_f32_16x16x32_bf16(af[i], bfr[j], acc[i][j], 0, 0, 0);
    }

    // ---- clip(s,-20,0)^2 partial sum (zero-padded rows/cols contribute exactly 0) ----
    float cs = 0.0f;
    #pragma unroll
    for (int i = 0; i < 4; ++i)
        #pragma unroll
        for (int j = 0; j < 7; ++j)
            #pragma unroll
            for (int r = 0; r < 4; ++r) {
                float v = acc[i][j][r];
                float cv = fminf(fmaxf(v, -20.0f), 0.0f);
                cs += cv * cv;
            }
    #pragma unroll
    for (int off = 32; off; off >>= 1) cs += __shfl_xor(cs, off, 64);
    if (lane == 0) redbuf[w] = cs;

    // ---- per-row max over valid cols (C/D layout: col=lane&15, row=q*4+reg) ----
    bool colv[7];
    #pragma unroll
    for (int j = 0; j < 7; ++j) colv[j] = (wc * 112 + j * 16 + m16) < NV_;
    #pragma unroll
    for (int i = 0; i < 4; ++i) {
        float mx[4] = {-3e38f, -3e38f, -3e38f, -3e38f};
        #pragma unroll
        for (int j = 0; j < 7; ++j)
            #pragma unroll
            for (int r = 0; r < 4; ++r)
                mx[r] = fmaxf(mx[r], colv[j] ? acc[i][j][r] : -3e38f);
        #pragma unroll
        for (int r = 0; r < 4; ++r) {
            float mm = mx[r];
            #pragma unroll
            for (int off = 1; off <= 8; off <<= 1) mm = fmaxf(mm, __shfl_xor(mm, off, 64));
            if (m16 == 0) maxred[wc][wr * 64 + i * 16 + q * 4 + r] = mm;
        }
    }
    __syncthreads();
    if (tid == 0) atomicAdd(accNonneg, redbuf[0] + redbuf[1] + redbuf[2] + redbuf[3]);
    if (tid < 128) {
        float mm = fmaxf(maxred[0][tid], maxred[1][tid]);
        int R = rowA0 + tid;
        if (R < M_) {
            int x = R / NA_, a = R - x * NA_;
            int y = yt / T_, t = yt - y * T_;
            maxvis[(((size_t)x * B_ + y) * NA_ + a) * T_ + t] = mm;
        }
    }
}

// ---------------- per-(x,y) aggregation over (a,t) ----------------
__global__ void aggregate_kernel(const float* __restrict__ maxvis,
                                 const float* __restrict__ thrPtr,
                                 const float* __restrict__ scalePtr,
                                 float* __restrict__ clipSims,
                                 float* __restrict__ accFrac,
                                 float* __restrict__ accSel)
{
    int xy = blockIdx.x;
    int x = xy / B_, y = xy % B_;
    int a = threadIdx.x;
    float th    = 1.0f / (1.0f + expf(-thrPtr[0]));
    float scale = scalePtr[0];
    float token = 0.0f, cnt = 0.0f, selsum = 0.0f;
    if (a < NA_) {
        const float* p = maxvis + (((size_t)x * B_ + y) * NA_ + a) * T_;
        float ws = 0.0f, ss = 0.0f;
        #pragma unroll
        for (int t = 0; t < T_; ++t) {
            float mv  = p[t];
            float rd  = mv - th;
            float sel = fmaxf(rd, 0.0f) * scale;
            ws += mv * sel;
            ss += sel;
            if (rd > 0.0f) cnt += 1.0f;
            if (x == y) selsum += 0.5f * (tanhf(20.0f * rd) + 1.0f);
        }
        token = ws / fmaxf(ss, 1e-6f);
    }
    #pragma unroll
    for (int off = 32; off; off >>= 1) {
        token  += __shfl_xor(token,  off, 64);
        cnt    += __shfl_xor(cnt,    off, 64);
        selsum += __shfl_xor(selsum, off, 64);
    }
    if (threadIdx.x == 0) {
        clipSims[x * B_ + y] = token / (float)NA_;
        atomicAdd(accFrac, cnt);
        if (x == y) atomicAdd(accSel, selsum);
    }
}

// ---------------- finalize ----------------
__global__ void finalize_kernel(const float* __restrict__ clipSims,
                                const float* __restrict__ accs,
                                const float* __restrict__ tempPtr,
                                const float* __restrict__ scalePtr,
                                const float* __restrict__ thrPtr,
                                float* __restrict__ out)
{
    __shared__ float cs[B_ * B_];
    int tid = threadIdx.x;  // 64
    for (int i = tid; i < B_ * B_; i += 64) cs[i] = clipSims[i];
    __syncthreads();
    float lsum = 0.0f;
    if (tid < B_) {
        int i = tid;
        float m = -1e30f;
        for (int j = 0; j < B_; ++j) m = fmaxf(m, cs[i * B_ + j]);
        float e = 0.0f;
        for (int j = 0; j < B_; ++j) e += expf(cs[i * B_ + j] - m);
        float la = m + logf(e) - cs[i * B_ + i];
        float m2 = -1e30f;
        for (int j = 0; j < B_; ++j) m2 = fmaxf(m2, cs[j * B_ + i]);
        float e2 = 0.0f;
        for (int j = 0; j < B_; ++j) e2 += expf(cs[j * B_ + i] - m2);
        float lv = m2 + logf(e2) - cs[i * B_ + i];
        lsum = la + lv;
    }
    #pragma unroll
    for (int off = 32; off; off >>= 1) lsum += __shfl_xor(lsum, off, 64);
    if (tid == 0) {
        float contrastive = lsum / (float)B_ * 0.5f;
        float temp = tempPtr[0], scl = scalePtr[0];
        float th = 1.0f / (1.0f + expf(-thrPtr[0]));
        float l_nonneg = accs[0] / 56448000.0f;   // B*B*NA*T*NV
        float logt = logf(temp);
        float tl  = fmaxf(-logt, 0.0f);
        float thi = fmaxf(logt - logf(4.0f), 0.0f);
        float l_cal = tl * tl + thi * thi;
        float t1 = fmaxf(th - 0.9f, 0.0f), t2 = fmaxf(0.1f - th, 0.0f);
        float l_thr = t1 * t1 + t2 * t2;
        float s1 = fmaxf(scl - 20.0f, 0.0f), s2 = fmaxf(1.0f - scl, 0.0f);
        float l_scale = s1 * s1 + s2 * s2;
        float reg = 0.15f * l_nonneg + 2.0f * l_cal + 0.1f * l_thr + 0.1f * l_scale;
        float frac   = accs[1] / 288000.0f;       // B*B*NA*T
        float selrew = -0.1f * log1pf(accs[2] / 12000.0f); // B*NA*T
        out[0] = selrew + contrastive + reg;
        out[1] = contrastive;
        out[2] = reg;
        out[3] = frac;
        out[4] = selrew;
    }
}

extern "C" void kernel_launch(void* const* d_in, const int* in_sizes, int n_in,
                              void* d_out, int out_size, void* d_ws, size_t ws_size,
                              hipStream_t stream) {
    const float* audio  = (const float*)d_in[0];  // (24,50,512)
    const float* visual = (const float*)d_in[1];  // (24,10,196,512)
    const float* temp   = (const float*)d_in[2];
    const float* scale  = (const float*)d_in[3];
    const float* thr    = (const float*)d_in[4];
    float* out = (float*)d_out;

    unsigned char* wsb = (unsigned char*)d_ws;
    unsigned short* Abf = (unsigned short*)wsb;                       // 1280*512*2    = 1,310,720 B
    unsigned short* Vbf = (unsigned short*)(wsb + 1310720);           // 53760*512*2   = 55,050,240 B
    float* maxvis   = (float*)(wsb + 1310720 + 55050240);             // 288000 floats = 1,152,000 B
    float* clipSims = (float*)(wsb + 1310720 + 55050240 + 1152000);   // 576 floats
    float* accs     = clipSims + 576;                                 // 3: [nonneg, frac, sel]

    hipMemsetAsync(accs, 0, 3 * sizeof(float), stream);

    normconvA_kernel<<<MPAD / 4, 256, 0, stream>>>(audio, temp, Abf);
    normconvV_kernel<<<VROWS / 4, 256, 0, stream>>>(visual, Vbf);

    dim3 grid(MPAD / 128, YT_);
    simred_kernel<<<grid, 256, 0, stream>>>(Abf, Vbf, maxvis, accs);

    aggregate_kernel<<<B_ * B_, 64, 0, stream>>>(maxvis, thr, scale, clipSims, accs + 1, accs + 2);
    finalize_kernel<<<1, 64, 0, stream>>>(clipSims, accs, temp, scale, thr, out);
}